// Round 9
// baseline (1377.520 us; speedup 1.0000x reference)
//
#include <hip/hip_runtime.h>
#include <cmath>

#define EPSF 1e-6f
#define TAUF 0.03f

typedef short bf16x8 __attribute__((ext_vector_type(8)));
typedef float f32x4 __attribute__((ext_vector_type(4)));

// ---------- helpers ----------
__device__ inline float wred_sum(float v) {
    #pragma unroll
    for (int d = 1; d < 64; d <<= 1) v += __shfl_xor(v, d);
    return v;
}
__device__ inline float wred_max(float v) {
    #pragma unroll
    for (int d = 1; d < 64; d <<= 1) v = fmaxf(v, __shfl_xor(v, d));
    return v;
}
__device__ inline short f2bf(float f) {
    unsigned u = __float_as_uint(f);
    unsigned lsb = (u >> 16) & 1u;
    u += 0x7fffu + lsb;
    return (short)(u >> 16);
}
__device__ inline float bf2f(short h) {
    return __uint_as_float(((unsigned)(unsigned short)h) << 16);
}
__device__ __forceinline__ void gld16(const void* g, void* l) {
    __builtin_amdgcn_global_load_lds(
        (const __attribute__((address_space(1))) unsigned int*)g,
        (__attribute__((address_space(3))) unsigned int*)l, 16, 0, 0);
}

// =================== pre-pass: weight conversion ===================
// w1 [256 oc][1024 c][3][3] fp32 -> Bf_hi/Bf_lo fragment layout [tap][c/8][oc 256][8ch]
__global__ __launch_bounds__(256) void cvt_w1_kernel(
    const float* __restrict__ w1, short* __restrict__ Bf_hi, short* __restrict__ Bf_lo) {
    int gt = blockIdx.x * 256 + threadIdx.x;      // 0..294911
    int oc  = gt & 255;
    int cg  = (gt >> 8) & 127;
    int tap = gt >> 15;                           // 0..8
    bf16x8 h8, l8;
    #pragma unroll
    for (int j = 0; j < 8; ++j) {
        float f = w1[(size_t)oc * 9216 + (size_t)(cg * 8 + j) * 9 + tap];
        short h = f2bf(f);
        h8[j] = h;
        l8[j] = f2bf(f - bf2f(h));
    }
    size_t idx = ((size_t)(tap * 128 + cg) * 256 + oc);
    *reinterpret_cast<bf16x8*>(Bf_hi + idx * 8) = h8;
    *reinterpret_cast<bf16x8*>(Bf_lo + idx * 8) = l8;
}

// =================== pre-pass: feature conversion (+fused zero padding) ===================
// feat [b][c][28][28] fp32 -> A_hi/A_lo [b][30 rows (y+1)][32 cols (x+1)][1024 c] bf16
__global__ __launch_bounds__(256) void cvt_feat_kernel(
    const float* __restrict__ feat, short* __restrict__ A_hi, short* __restrict__ A_lo) {
    const int cg = blockIdx.x;   // 0..3
    const int y  = blockIdx.y;   // 0..27
    const int b  = blockIdx.z;
    const int tid = threadIdx.x;
    __shared__ float tile[256][29];
    const int c = cg * 256 + tid;
    const float* fp = feat + ((size_t)(b * 1024 + c) * 28 + y) * 28;
    #pragma unroll
    for (int j = 0; j < 7; ++j) {
        float4 v = *reinterpret_cast<const float4*>(fp + 4 * j);
        tile[tid][4 * j + 0] = v.x; tile[tid][4 * j + 1] = v.y;
        tile[tid][4 * j + 2] = v.z; tile[tid][4 * j + 3] = v.w;
    }
    __syncthreads();
    size_t base = ((size_t)(b * 30 + y + 1) * 32) * 1024 + c;
    #pragma unroll
    for (int j = 0; j < 28; ++j) {
        float v = tile[tid][j];
        short h = f2bf(v);
        short lo = f2bf(v - bf2f(h));
        size_t o = base + (size_t)(j + 1) * 1024;
        A_hi[o] = h; A_lo[o] = lo;
    }
    // fused zero padding (replaces memsets):
    A_hi[base] = 0; A_lo[base] = 0;
    #pragma unroll
    for (int col = 29; col < 32; ++col) {
        A_hi[base + (size_t)col * 1024] = 0;
        A_lo[base + (size_t)col * 1024] = 0;
    }
    if (y == 0) {
        size_t r0 = ((size_t)(b * 30 + 0) * 32) * 1024 + c;
        #pragma unroll
        for (int col = 0; col < 32; ++col) {
            A_hi[r0 + (size_t)col * 1024] = 0;
            A_lo[r0 + (size_t)col * 1024] = 0;
        }
    }
    if (y == 27) {
        size_t r29 = ((size_t)(b * 30 + 29) * 32) * 1024 + c;
        #pragma unroll
        for (int col = 0; col < 32; ++col) {
            A_hi[r29 + (size_t)col * 1024] = 0;
            A_lo[r29 + (size_t)col * 1024] = 0;
        }
    }
}

// B fragment loader: 4 n-frags x {hi,lo} straight to VGPRs
__device__ __forceinline__ void loadB(bf16x8* dst, const short* __restrict__ Bf_hi,
                                      const short* __restrict__ Bf_lo,
                                      int tap, int c0, int lane_off) {
    const bf16x8* ph = reinterpret_cast<const bf16x8*>(Bf_hi) +
                       ((size_t)(tap * 128 + (c0 >> 3)) * 256 + lane_off);
    const bf16x8* pl = reinterpret_cast<const bf16x8*>(Bf_lo) +
                       ((size_t)(tap * 128 + (c0 >> 3)) * 256 + lane_off);
    #pragma unroll
    for (int n = 0; n < 4; ++n) {
        dst[n]     = ph[16 * n];
        dst[4 + n] = pl[16 * n];
    }
}

// =================== K1: conv3x3 (split-bf16 MFMA, A in LDS, B in regs) + fused 1x1 head ===================
// grid (7 ty, 32 b), 256 thr (4 waves). Block tile 112 px x 256 oc; wave = 112 px x 64 oc (m=7,n=4).
__global__ __launch_bounds__(256) void conv_logits_kernel(
    const short* __restrict__ A_hi, const short* __restrict__ A_lo,
    const short* __restrict__ Bf_hi, const short* __restrict__ Bf_lo,
    const float* __restrict__ b1, const float* __restrict__ w2,
    const float* __restrict__ b2, float* __restrict__ logits) {
    const int ty = blockIdx.x;    // 0..6
    const int b  = blockIdx.y;
    const int tid = threadIdx.x;
    const int lane = tid & 63, wv = tid >> 6;
    const int l15 = lane & 15, q = lane >> 4;

    __shared__ __align__(16) short AsH[2][6144];   // [buf][6 rows][32 cols][32 ch swizzled]
    __shared__ __align__(16) short AsL[2][6144];
    __shared__ float w2s[12][256];
    __shared__ float part[4][12][112];

    for (int i = tid; i < 3072; i += 256) w2s[i >> 8][i & 255] = w2[i];

    // A staging source offsets
    int a_src[3];
    #pragma unroll
    for (int j = 0; j < 3; ++j) {
        int qq = tid + 256 * j;             // 0..767
        int cell = qq >> 2, sub = qq & 3;
        int row = cell >> 5, col = cell & 31;
        a_src[j] = ((b * 30 + 4 * ty + row) * 32 + col) * 1024 + 8 * (sub ^ ((col >> 1) & 3));
    }
    // A fragment read offsets (bytes)
    int rowb[7], colb[7][3];
    #pragma unroll
    for (int f = 0; f < 7; ++f) {
        int m = 16 * f + l15;
        int yl = m / 28, x = m % 28;
        rowb[f] = yl * 2048;
        #pragma unroll
        for (int kx = 0; kx < 3; ++kx) {
            int cc = x + kx;
            colb[f][kx] = cc * 64 + ((q ^ ((cc >> 1) & 3)) << 4);
        }
    }
    const int bfrag_lane = q * 256 + 64 * wv + l15;   // kslot*256 + oc

    f32x4 acc[7][4];
    #pragma unroll
    for (int f = 0; f < 7; ++f)
        #pragma unroll
        for (int n = 0; n < 4; ++n) acc[f][n] = (f32x4){0.f, 0.f, 0.f, 0.f};

    bf16x8 breg[2][8];

    // prime: A chunk0 + B(tap0,chunk0)
    #pragma unroll
    for (int j = 0; j < 3; ++j) {
        gld16(A_hi + a_src[j], (char*)AsH[0] + (tid + 256 * j) * 16);
        gld16(A_lo + a_src[j], (char*)AsL[0] + (tid + 256 * j) * 16);
    }
    loadB(breg[0], Bf_hi, Bf_lo, 0, 0, bfrag_lane);
    __syncthreads();

    for (int ci = 0; ci < 32; ++ci) {
        const int c0 = ci * 32;
        const int p = ci & 1;
        if (ci < 31) {
            #pragma unroll
            for (int j = 0; j < 3; ++j) {
                gld16(A_hi + a_src[j] + c0 + 32, (char*)AsH[p ^ 1] + (tid + 256 * j) * 16);
                gld16(A_lo + a_src[j] + c0 + 32, (char*)AsL[p ^ 1] + (tid + 256 * j) * 16);
            }
        }
        #pragma unroll
        for (int tap = 0; tap < 9; ++tap) {
            // FIX (round 6): buffer parity must follow the LINEAR prefetch index
            // ci*9+tap (9 odd => parity == (ci+tap)&1), not tap&1. With tap&1 the
            // chunk boundary consumed stale tap-8 weights as tap-0 from chunk 1 on.
            const int par = (ci + tap) & 1;
            if (tap < 8) loadB(breg[par ^ 1], Bf_hi, Bf_lo, tap + 1, c0, bfrag_lane);
            else if (ci < 31) loadB(breg[par ^ 1], Bf_hi, Bf_lo, 0, c0 + 32, bfrag_lane);
            const int ky = tap / 3, kx = tap - 3 * (tap / 3);
            #pragma unroll
            for (int f = 0; f < 7; ++f) {
                const int off = rowb[f] + ky * 2048 + colb[f][kx];
                bf16x8 ah = *reinterpret_cast<const bf16x8*>((const char*)AsH[p] + off);
                bf16x8 al = *reinterpret_cast<const bf16x8*>((const char*)AsL[p] + off);
                #pragma unroll
                for (int n = 0; n < 4; ++n) {
                    acc[f][n] = __builtin_amdgcn_mfma_f32_16x16x32_bf16(ah, breg[par][n],     acc[f][n], 0, 0, 0);
                    acc[f][n] = __builtin_amdgcn_mfma_f32_16x16x32_bf16(ah, breg[par][4 + n], acc[f][n], 0, 0, 0);
                    acc[f][n] = __builtin_amdgcn_mfma_f32_16x16x32_bf16(al, breg[par][n],     acc[f][n], 0, 0, 0);
                }
            }
        }
        __syncthreads();
    }

    // ---- fused epilogue: bias+relu, 1x1 conv via w2 dot + 16-lane butterfly ----
    float b1v[4], wk[12][4];
    #pragma unroll
    for (int n = 0; n < 4; ++n) b1v[n] = b1[64 * wv + 16 * n + l15];
    #pragma unroll
    for (int k = 0; k < 12; ++k)
        #pragma unroll
        for (int n = 0; n < 4; ++n) wk[k][n] = w2s[k][64 * wv + 16 * n + l15];

    #pragma unroll
    for (int f = 0; f < 7; ++f) {
        #pragma unroll
        for (int r = 0; r < 4; ++r) {
            float v0 = fmaxf(acc[f][0][r] + b1v[0], 0.f);
            float v1 = fmaxf(acc[f][1][r] + b1v[1], 0.f);
            float v2 = fmaxf(acc[f][2][r] + b1v[2], 0.f);
            float v3 = fmaxf(acc[f][3][r] + b1v[3], 0.f);
            float sk[12];
            #pragma unroll
            for (int k = 0; k < 12; ++k)
                sk[k] = v0 * wk[k][0] + v1 * wk[k][1] + v2 * wk[k][2] + v3 * wk[k][3];
            #pragma unroll
            for (int d = 1; d < 16; d <<= 1)
                #pragma unroll
                for (int k = 0; k < 12; ++k) sk[k] += __shfl_xor(sk[k], d);
            float outv = 0.f;
            #pragma unroll
            for (int k = 0; k < 12; ++k) outv = (l15 == k) ? sk[k] : outv;
            if (l15 < 12) part[wv][l15][16 * f + 4 * q + r] = outv;
        }
    }
    __syncthreads();
    for (int idx = tid; idx < 1344; idx += 256) {
        int k = idx / 112, pl = idx - k * 112;
        int pp = ty * 112 + pl;
        float s = part[0][k][pl] + part[1][k][pl] + part[2][k][pl] + part[3][k][pl] + b2[k];
        float gx = (float)(pp % 28) * (1.f / 27.f);
        float gy = (float)(pp / 28) * (1.f / 27.f);
        float cxk = 0.15f + (0.7f / 3.f) * (float)(k & 3);
        float cyk = 0.15f + 0.35f * (float)(k >> 2);
        float dx = gx - cxk, dy = gy - cyk;
        float prior = -(dx * dx + dy * dy) / (2.f * 0.22f * 0.22f);
        logits[(size_t)b * 9408 + k * 784 + pp] = s + 0.15f * prior;
    }
}

// =================== K2: softmax + norms + coords + loss partials ===================
__global__ __launch_bounds__(256) void head2_kernel(
    const float* __restrict__ logits, float* __restrict__ out,
    float* __restrict__ partials) {
    const int b = blockIdx.x;
    const int tid = threadIdx.x;
    const int lane = tid & 63;
    const int wv = tid >> 6;

    __shared__ float lg[12][784];
    __shared__ float kN[12], kE[12], cx_s[12], cy_s[12];
    __shared__ float redD[4];
    __shared__ float redS;

    for (int idx = tid; idx < 9408; idx += 256)
        ((float*)lg)[idx] = logits[(size_t)b * 9408 + idx];
    __syncthreads();

    for (int k = wv; k < 12; k += 4) {
        float m = -1e30f;
        for (int p = lane; p < 784; p += 64) m = fmaxf(m, lg[k][p]);
        m = wred_max(m);
        float mz = m / TAUF;
        float s = 0.f;
        for (int p = lane; p < 784; p += 64) {
            float e = expf(lg[k][p] / TAUF - mz);
            lg[k][p] = e;
            s += e;
        }
        s = wred_sum(s);
        float inv = 1.f / s;
        for (int p = lane; p < 784; p += 64) lg[k][p] *= inv;
    }
    __syncthreads();

    for (int p = tid; p < 784; p += 256) {
        float s12 = 0.f;
        #pragma unroll
        for (int k = 0; k < 12; ++k) s12 += lg[k][p];
        s12 += EPSF;
        float inv = 1.f / s12;
        #pragma unroll
        for (int k = 0; k < 12; ++k) lg[k][p] *= inv;
    }
    __syncthreads();

    for (int k = wv; k < 12; k += 4) {
        float S = 0.f;
        for (int p = lane; p < 784; p += 64) S += lg[k][p];
        S = wred_sum(S);
        float invS = 1.f / fmaxf(S, EPSF);
        float xs = 0.f, ys = 0.f, sp = 0.f, ent = 0.f, n2 = 0.f;
        for (int p = lane; p < 784; p += 64) {
            float v = lg[k][p] * invS;
            lg[k][p] = v;
            out[(size_t)b * 9408 + k * 784 + p] = v;
            float gx = (float)(p % 28) * (1.f / 27.f);
            float gy = (float)(p / 28) * (1.f / 27.f);
            xs += v * gx; ys += v * gy; sp += v;
            float vc = fmaxf(v, EPSF);
            ent -= vc * logf(vc);
            n2 += v * v;
        }
        xs = wred_sum(xs); ys = wred_sum(ys); sp = wred_sum(sp);
        ent = wred_sum(ent); n2 = wred_sum(n2);
        if (lane == 0) {
            float spc = fmaxf(sp, EPSF);
            float cx = xs / spc, cy = ys / spc;
            cx_s[k] = cx; cy_s[k] = cy;
            out[301056 + (size_t)b * 24 + 2 * k]     = cx;
            out[301056 + (size_t)b * 24 + 2 * k + 1] = cy;
            kN[k] = fmaxf(sqrtf(n2), EPSF);
            kE[k] = ent;
        }
    }
    __syncthreads();

    float divp = 0.f;
    int pi = 0;
    for (int k = 0; k < 12; ++k) {
        for (int j = k + 1; j < 12; ++j) {
            if ((pi & 3) == wv) {
                float dot = 0.f;
                for (int p = lane; p < 784; p += 64) dot += lg[k][p] * lg[j][p];
                dot = wred_sum(dot);
                float simv = dot / (kN[k] * kN[j]);
                divp += 2.f * simv * simv;
            }
            ++pi;
        }
    }
    if (lane == 0) redD[wv] = divp;
    if (wv == 0) {
        float ssum = 0.f;
        for (int pr = lane; pr < 132; pr += 64) {
            int k = pr / 11; int jj = pr % 11; int j = jj + (jj >= k ? 1 : 0);
            float dx = cx_s[k] - cx_s[j], dy = cy_s[k] - cy_s[j];
            float d2 = dx * dx + dy * dy;
            float dist = sqrtf(fmaxf(d2, 1e-12f));
            ssum += 1.f / fmaxf(dist, EPSF);
        }
        ssum = wred_sum(ssum);
        if (lane == 0) redS = ssum;
    }
    __syncthreads();
    if (tid == 0) {
        float db = redD[0] + redD[1] + redD[2] + redD[3];
        float eb = 0.f;
        #pragma unroll
        for (int k = 0; k < 12; ++k) eb += kE[k];
        partials[b]      = db;
        partials[32 + b] = eb;
        partials[64 + b] = redS;
    }
}

// =================== K3: feat_k einsum ===================
__global__ __launch_bounds__(128) void featk2_kernel(
    const float* __restrict__ feat, const float* __restrict__ probs,
    float* __restrict__ outfk) {
    const int cg = blockIdx.x, b = blockIdx.y;
    const int tid = threadIdx.x;
    __shared__ float ps[12 * 784];
    for (int idx = tid; idx < 9408; idx += 128) ps[idx] = probs[(size_t)b * 9408 + idx];
    __syncthreads();
    const int c = cg * 128 + tid;
    const float* fp = &feat[((size_t)b * 1024 + c) * 784];
    float acc[12];
    #pragma unroll
    for (int k = 0; k < 12; ++k) acc[k] = 0.f;
    for (int pc = 0; pc < 784; pc += 4) {
        float4 f4 = *reinterpret_cast<const float4*>(fp + pc);
        #pragma unroll
        for (int k = 0; k < 12; ++k) {
            float4 p4 = *reinterpret_cast<const float4*>(&ps[k * 784 + pc]);
            acc[k] += f4.x * p4.x + f4.y * p4.y + f4.z * p4.z + f4.w * p4.w;
        }
    }
    #pragma unroll
    for (int k = 0; k < 12; ++k)
        outfk[(size_t)b * 12288 + k * 1024 + c] = acc[k] * (1.f / 784.f);
}

// =================== K4: reduce partials ===================
__global__ void finalize_kernel(const float* __restrict__ part, float* __restrict__ out) {
    int t = threadIdx.x;
    float d = t < 32 ? part[t]      : 0.f;
    float e = t < 32 ? part[32 + t] : 0.f;
    float s = t < 32 ? part[64 + t] : 0.f;
    d = wred_sum(d); e = wred_sum(e); s = wred_sum(s);
    if (t == 0) {
        out[695040] = d / 4608.f;
        out[695041] = e / 384.f;
        out[695042] = s / (4224.f + 1e-6f);
    }
}

// =================== fallback fp32 path (round-3, verified) ===================
__global__ __launch_bounds__(256) void conv3x3_relu_kernel(
    const float* __restrict__ feat, const float* __restrict__ w1,
    const float* __restrict__ b1, float* __restrict__ h1) {
    const int ty = blockIdx.x;
    const int og = blockIdx.y;
    const int b  = blockIdx.z;
    const int tid = threadIdx.x;
    const int g = tid >> 4;
    const int qq = tid & 15;
    const int r  = g >> 2;
    const int x0 = (g & 3) * 7;
    __shared__ float fs[4][6][32];
    __shared__ float ws_[64][37];
    float acc[4][7];
    #pragma unroll
    for (int o = 0; o < 4; ++o)
        #pragma unroll
        for (int px = 0; px < 7; ++px) acc[o][px] = 0.f;
    const int y_base = ty * 4 - 1;
    for (int cc = 0; cc < 256; ++cc) {
        const int c0 = cc * 4;
        for (int idx = tid; idx < 768; idx += 256) {
            int cb = idx / 192; int rem = idx - cb * 192;
            int row = rem >> 5; int xi = rem & 31;
            int y = y_base + row; int x = xi - 1;
            float v = 0.f;
            if (xi < 30 && (unsigned)y < 28u && (unsigned)x < 28u)
                v = feat[(((size_t)b * 1024 + c0 + cb) * 28 + y) * 28 + x];
            fs[cb][row][xi] = v;
        }
        for (int idx = tid; idx < 2304; idx += 256) {
            int ocl = idx / 36; int t36 = idx - ocl * 36;
            ws_[ocl][t36] = w1[(size_t)(og * 64 + ocl) * 9216 + (size_t)c0 * 9 + t36];
        }
        __syncthreads();
        #pragma unroll
        for (int cb = 0; cb < 4; ++cb) {
            float f[3][9];
            #pragma unroll
            for (int dy = 0; dy < 3; ++dy)
                #pragma unroll
                for (int i = 0; i < 9; ++i) f[dy][i] = fs[cb][r + dy][x0 + i];
            #pragma unroll
            for (int o = 0; o < 4; ++o) {
                float w9[9];
                #pragma unroll
                for (int t = 0; t < 9; ++t) w9[t] = ws_[qq * 4 + o][cb * 9 + t];
                #pragma unroll
                for (int px = 0; px < 7; ++px)
                    #pragma unroll
                    for (int ky = 0; ky < 3; ++ky)
                        #pragma unroll
                        for (int kx = 0; kx < 3; ++kx)
                            acc[o][px] += f[ky][px + kx] * w9[ky * 3 + kx];
            }
        }
        __syncthreads();
    }
    const int oc = og * 64 + qq * 4;
    const float4 bv = *reinterpret_cast<const float4*>(&b1[oc]);
    const int prow = ty * 4 + r;
    #pragma unroll
    for (int px = 0; px < 7; ++px) {
        int p = prow * 28 + x0 + px;
        float4 o4;
        o4.x = fmaxf(acc[0][px] + bv.x, 0.f);
        o4.y = fmaxf(acc[1][px] + bv.y, 0.f);
        o4.z = fmaxf(acc[2][px] + bv.z, 0.f);
        o4.w = fmaxf(acc[3][px] + bv.w, 0.f);
        *reinterpret_cast<float4*>(&h1[((size_t)(b * 784 + p)) * 256 + oc]) = o4;
    }
}

__global__ __launch_bounds__(256) void head_kernel(
    const float* __restrict__ h1, const float* __restrict__ w2,
    const float* __restrict__ b2, float* __restrict__ out,
    float* __restrict__ partials) {
    const int b = blockIdx.x;
    const int tid = threadIdx.x;
    const int lane = tid & 63;
    const int wv = tid >> 6;
    __shared__ float lg[12][784];
    __shared__ float w2s[12][256];
    __shared__ float kN[12], kE[12], cx_s[12], cy_s[12];
    __shared__ float redD[4];
    __shared__ float redS;
    for (int idx = tid; idx < 3072; idx += 256) w2s[idx >> 8][idx & 255] = w2[idx];
    float bias[12];
    #pragma unroll
    for (int k = 0; k < 12; ++k) bias[k] = b2[k];
    __syncthreads();
    for (int p = tid; p < 784; p += 256) {
        float acc[12];
        #pragma unroll
        for (int k = 0; k < 12; ++k) acc[k] = bias[k];
        const float* hp = &h1[((size_t)(b * 784 + p)) * 256];
        for (int c = 0; c < 256; c += 4) {
            float4 hv = *reinterpret_cast<const float4*>(hp + c);
            #pragma unroll
            for (int k = 0; k < 12; ++k) {
                float4 wq = *reinterpret_cast<const float4*>(&w2s[k][c]);
                acc[k] += hv.x * wq.x + hv.y * wq.y + hv.z * wq.z + hv.w * wq.w;
            }
        }
        float gx = (float)(p % 28) * (1.f / 27.f);
        float gy = (float)(p / 28) * (1.f / 27.f);
        #pragma unroll
        for (int k = 0; k < 12; ++k) {
            float cxk = 0.15f + (0.7f / 3.f) * (float)(k & 3);
            float cyk = 0.15f + 0.35f * (float)(k >> 2);
            float dx = gx - cxk, dy = gy - cyk;
            float prior = -(dx * dx + dy * dy) / (2.f * 0.22f * 0.22f);
            lg[k][p] = acc[k] + 0.15f * prior;
        }
    }
    __syncthreads();
    for (int k = wv; k < 12; k += 4) {
        float m = -1e30f;
        for (int p = lane; p < 784; p += 64) m = fmaxf(m, lg[k][p]);
        m = wred_max(m);
        float mz = m / TAUF;
        float s = 0.f;
        for (int p = lane; p < 784; p += 64) {
            float e = expf(lg[k][p] / TAUF - mz);
            lg[k][p] = e;
            s += e;
        }
        s = wred_sum(s);
        float inv = 1.f / s;
        for (int p = lane; p < 784; p += 64) lg[k][p] *= inv;
    }
    __syncthreads();
    for (int p = tid; p < 784; p += 256) {
        float s12 = 0.f;
        #pragma unroll
        for (int k = 0; k < 12; ++k) s12 += lg[k][p];
        s12 += EPSF;
        float inv = 1.f / s12;
        #pragma unroll
        for (int k = 0; k < 12; ++k) lg[k][p] *= inv;
    }
    __syncthreads();
    for (int k = wv; k < 12; k += 4) {
        float S = 0.f;
        for (int p = lane; p < 784; p += 64) S += lg[k][p];
        S = wred_sum(S);
        float invS = 1.f / fmaxf(S, EPSF);
        float xs = 0.f, ys = 0.f, sp = 0.f, ent = 0.f, n2 = 0.f;
        for (int p = lane; p < 784; p += 64) {
            float v = lg[k][p] * invS;
            lg[k][p] = v;
            out[(size_t)b * 9408 + k * 784 + p] = v;
            float gx = (float)(p % 28) * (1.f / 27.f);
            float gy = (float)(p / 28) * (1.f / 27.f);
            xs += v * gx; ys += v * gy; sp += v;
            float vc = fmaxf(v, EPSF);
            ent -= vc * logf(vc);
            n2 += v * v;
        }
        xs = wred_sum(xs); ys = wred_sum(ys); sp = wred_sum(sp);
        ent = wred_sum(ent); n2 = wred_sum(n2);
        if (lane == 0) {
            float spc = fmaxf(sp, EPSF);
            float cx = xs / spc, cy = ys / spc;
            cx_s[k] = cx; cy_s[k] = cy;
            out[301056 + (size_t)b * 24 + 2 * k]     = cx;
            out[301056 + (size_t)b * 24 + 2 * k + 1] = cy;
            kN[k] = fmaxf(sqrtf(n2), EPSF);
            kE[k] = ent;
        }
    }
    __syncthreads();
    float divp = 0.f;
    int pi = 0;
    for (int k = 0; k < 12; ++k) {
        for (int j = k + 1; j < 12; ++j) {
            if ((pi & 3) == wv) {
                float dot = 0.f;
                for (int p = lane; p < 784; p += 64) dot += lg[k][p] * lg[j][p];
                dot = wred_sum(dot);
                float simv = dot / (kN[k] * kN[j]);
                divp += 2.f * simv * simv;
            }
            ++pi;
        }
    }
    if (lane == 0) redD[wv] = divp;
    if (wv == 0) {
        float ssum = 0.f;
        for (int pr = lane; pr < 132; pr += 64) {
            int k = pr / 11; int jj = pr % 11; int j = jj + (jj >= k ? 1 : 0);
            float dx = cx_s[k] - cx_s[j], dy = cy_s[k] - cy_s[j];
            float d2 = dx * dx + dy * dy;
            float dist = sqrtf(fmaxf(d2, 1e-12f));
            ssum += 1.f / fmaxf(dist, EPSF);
        }
        ssum = wred_sum(ssum);
        if (lane == 0) redS = ssum;
    }
    __syncthreads();
    if (tid == 0) {
        float db = redD[0] + redD[1] + redD[2] + redD[3];
        float eb = 0.f;
        #pragma unroll
        for (int k = 0; k < 12; ++k) eb += kE[k];
        partials[b]      = db;
        partials[32 + b] = eb;
        partials[64 + b] = redS;
    }
}

__global__ __launch_bounds__(256) void featk_kernel(
    const float* __restrict__ feat, const float* __restrict__ probs,
    float* __restrict__ outfk) {
    const int cg = blockIdx.x, b = blockIdx.y;
    const int tid = threadIdx.x;
    __shared__ float ps[12 * 784];
    for (int idx = tid; idx < 9408; idx += 256) ps[idx] = probs[(size_t)b * 9408 + idx];
    __syncthreads();
    const int c = cg * 256 + tid;
    const float* fp = &feat[((size_t)b * 1024 + c) * 784];
    float acc[12];
    #pragma unroll
    for (int k = 0; k < 12; ++k) acc[k] = 0.f;
    for (int pc = 0; pc < 784; pc += 4) {
        float4 f4 = *reinterpret_cast<const float4*>(fp + pc);
        #pragma unroll
        for (int k = 0; k < 12; ++k) {
            float4 p4 = *reinterpret_cast<const float4*>(&ps[k * 784 + pc]);
            acc[k] += f4.x * p4.x + f4.y * p4.y + f4.z * p4.z + f4.w * p4.w;
        }
    }
    #pragma unroll
    for (int k = 0; k < 12; ++k)
        outfk[(size_t)b * 12288 + k * 1024 + c] = acc[k] * (1.f / 784.f);
}

// =================== launch ===================
extern "C" void kernel_launch(void* const* d_in, const int* in_sizes, int n_in,
                              void* d_out, int out_size, void* d_ws, size_t ws_size,
                              hipStream_t stream) {
    const float* feat = (const float*)d_in[0];
    const float* w1   = (const float*)d_in[1];
    const float* b1   = (const float*)d_in[2];
    const float* w2   = (const float*)d_in[3];
    const float* b2   = (const float*)d_in[4];
    float* out = (float*)d_out;

    // ws layout
    float* h1     = (float*)d_ws;                  // fallback only
    float* logits = h1 + 6422528;                  // 301,056 f
    float* part   = logits + 301056;               // 96 f
    short* A_hi   = (short*)((char*)d_ws + 26894848);
    short* A_lo   = A_hi + 31457280;
    short* Bf_hi  = A_lo + 31457280;
    short* Bf_lo  = Bf_hi + 2359296;
    const size_t NEED = 162161152;

    if (ws_size >= NEED) {
        cvt_w1_kernel<<<1152, 256, 0, stream>>>(w1, Bf_hi, Bf_lo);
        cvt_feat_kernel<<<dim3(4, 28, 32), 256, 0, stream>>>(feat, A_hi, A_lo);
        conv_logits_kernel<<<dim3(7, 32), 256, 0, stream>>>(A_hi, A_lo, Bf_hi, Bf_lo,
                                                            b1, w2, b2, logits);
        head2_kernel<<<32, 256, 0, stream>>>(logits, out, part);
        featk2_kernel<<<dim3(8, 32), 128, 0, stream>>>(feat, out, out + 301824);
        finalize_kernel<<<1, 64, 0, stream>>>(part, out);
    } else {
        conv3x3_relu_kernel<<<dim3(7, 4, 32), 256, 0, stream>>>(feat, w1, b1, h1);
        head_kernel<<<32, 256, 0, stream>>>(h1, w2, b2, out, part);
        featk_kernel<<<dim3(4, 32), 256, 0, stream>>>(feat, out, out + 301824);
        finalize_kernel<<<1, 64, 0, stream>>>(part, out);
    }
}